// Round 5
// baseline (84.470 us; speedup 1.0000x reference)
//
#include <hip/hip_runtime.h>

typedef float v2f __attribute__((ext_vector_type(2)));

constexpr int H = 512, W = 512;   // fixed by the problem (4,3,512,512)
constexpr int K = 5, PADR = 2;

__device__ inline float readlane_f(float v, int l) {
    union { float f; int i; } u; u.f = v;
    u.i = __builtin_amdgcn_readlane(u.i, l);   // l may be a uniform SGPR
    return u.f;
}

// 4 pixels per thread. Row-streamed: #pragma unroll 1 on the row loop keeps
// only one 8-wide row live (~45 VGPRs) so 8 waves/SIMD can hide exp + load
// latency. Spatial log2-weights broadcast per-row via readlane (uniform idx).
__global__ __launch_bounds__(256) void bilateral_kernel(
    const float* __restrict__ x,
    const float* __restrict__ sk,
    const float* __restrict__ sigma_color,
    float* __restrict__ out)
{
    int t = threadIdx.x;
    int lane = t & 63;

    // one v_log, 25 values held in lanes 0..24; broadcast on demand
    float skl = sk[lane < K * K ? lane : 0];
    float vlog = __builtin_amdgcn_logf(skl);            // v_log_f32 = log2

    float s = sigma_color[0];                           // wave-uniform
    float c2 = -1.4426950408889634f / (2.0f * s * s);   // -log2(e)/(2s^2)
    v2f c2v = { c2, c2 };

    int gid = blockIdx.x * 256 + t;
    int p0 = gid << 2;                 // first of 4 pixels (grid exactly covers)
    int w0 = p0 & (W - 1);             // multiple of 4 -> float4 aligned
    int row = p0 >> 9;
    int h = row & (H - 1);
    int plane = row >> 9;
    const float* xp = x + (size_t)plane * (H * W);

    // reflected halo columns (only w0==0 / w0==508 actually reflect)
    int wl0 = w0 - 2; wl0 = (wl0 < 0) ? -wl0 : wl0;
    int wl1 = w0 - 1; wl1 = (wl1 < 0) ? -wl1 : wl1;
    int wr0 = w0 + 4; wr0 = (wr0 >= W) ? (2 * W - 2 - wr0) : wr0;
    int wr1 = w0 + 5; wr1 = (wr1 >= W) ? (2 * W - 2 - wr1) : wr1;

    // centers (row h, cols w0..w0+3)
    float4 c = *(const float4*)(xp + (h << 9) + w0);
    v2f cA = { c.x, c.y }, cB = { c.z, c.w };
    v2f wsA = {0.f, 0.f}, wsB = {0.f, 0.f};
    v2f accA = {0.f, 0.f}, accB = {0.f, 0.f};

#pragma unroll 1
    for (int i = 0; i < K; ++i) {
        int hv = h + i - PADR;                    // reflect: -1->1, H->H-2
        hv = (hv < 0) ? -hv : hv;
        hv = (hv >= H) ? (2 * H - 2 - hv) : hv;
        const float* rp = xp + (hv << 9);

        float rowv[8];
        float4 m = *(const float4*)(rp + w0);
        rowv[0] = rp[wl0];
        rowv[1] = rp[wl1];
        rowv[2] = m.x; rowv[3] = m.y; rowv[4] = m.z; rowv[5] = m.w;
        rowv[6] = rp[wr0];
        rowv[7] = rp[wr1];

        int lbase = i * K;                        // uniform
#pragma unroll
        for (int j = 0; j < K; ++j) {
            float lwv = readlane_f(vlog, lbase + j);
            v2f lsp = { lwv, lwv };
            v2f vA = { rowv[j],     rowv[j + 1] };
            v2f vB = { rowv[j + 2], rowv[j + 3] };
            v2f dA = vA - cA;
            v2f dB = vB - cB;
            v2f argA = __builtin_elementwise_fma(dA * c2v, dA, lsp);
            v2f argB = __builtin_elementwise_fma(dB * c2v, dB, lsp);
            v2f wA, wB;
            wA[0] = __builtin_amdgcn_exp2f(argA[0]);
            wA[1] = __builtin_amdgcn_exp2f(argA[1]);
            wB[0] = __builtin_amdgcn_exp2f(argB[0]);
            wB[1] = __builtin_amdgcn_exp2f(argB[1]);
            wsA += wA;
            wsB += wB;
            accA = __builtin_elementwise_fma(wA, vA, accA);
            accB = __builtin_elementwise_fma(wB, vB, accB);
        }
    }

    float4 o;
    o.x = accA[0] * __builtin_amdgcn_rcpf(wsA[0] + 1e-8f);
    o.y = accA[1] * __builtin_amdgcn_rcpf(wsA[1] + 1e-8f);
    o.z = accB[0] * __builtin_amdgcn_rcpf(wsB[0] + 1e-8f);
    o.w = accB[1] * __builtin_amdgcn_rcpf(wsB[1] + 1e-8f);
    *(float4*)(out + p0) = o;
}

extern "C" void kernel_launch(void* const* d_in, const int* in_sizes, int n_in,
                              void* d_out, int out_size, void* d_ws, size_t ws_size,
                              hipStream_t stream) {
    const float* x  = (const float*)d_in[0];
    const float* sk = (const float*)d_in[1];
    const float* sc = (const float*)d_in[2];
    float* out = (float*)d_out;

    const int total = in_sizes[0];             // 3,145,728
    const int blocks = total / (256 * 4);      // 3072, exact cover
    bilateral_kernel<<<blocks, 256, 0, stream>>>(x, sk, sc, out);
}

// Round 6
// 83.001 us; speedup vs baseline: 1.0177x; 1.0177x over previous
//
#include <hip/hip_runtime.h>

typedef float v2f __attribute__((ext_vector_type(2)));

constexpr int H = 512, W = 512;   // fixed by the problem (4,3,512,512)
constexpr int K = 5, PADR = 2;

__device__ inline float readlane_f(float v, int l) {
    union { float f; int i; } u; u.f = v;
    u.i = __builtin_amdgcn_readlane(u.i, l);
    return u.f;
}

// Best-measured variant (R4): 8 pixels per thread along W (4 v2f pairs).
// Window 5x12 fully hoisted: two aligned float4 loads + 4 scalar halo loads
// per row, branchless reflect, then one pure-compute block with high ILP.
// log2(spatial) broadcast to SGPRs via readlane — no prep kernel, no LDS.
__global__ __launch_bounds__(256) void bilateral_kernel(
    const float* __restrict__ x,
    const float* __restrict__ sk,
    const float* __restrict__ sigma_color,
    float* __restrict__ out)
{
    int t = threadIdx.x;
    int lane = t & 63;

    // lanes 0..24 of every wave: vlog = log2(sk[lane]); broadcast via readlane
    float skl = sk[lane < K * K ? lane : 0];
    float vlog = __builtin_amdgcn_logf(skl);          // v_log_f32 = log2
    float lsk[K * K];
#pragma unroll
    for (int k = 0; k < K * K; ++k) lsk[k] = readlane_f(vlog, k);

    float s = sigma_color[0];                          // wave-uniform
    float c2 = -1.4426950408889634f / (2.0f * s * s);  // -log2(e)/(2s^2)
    v2f c2v = { c2, c2 };

    int gid = blockIdx.x * 256 + t;
    int p0 = gid << 3;                 // first of 8 pixels (grid exactly covers)
    int w0 = p0 & (W - 1);             // multiple of 8 -> float4 aligned x2
    int row = p0 >> 9;
    int h = row & (H - 1);
    int plane = row >> 9;
    const float* xp = x + (size_t)plane * (H * W);

    // reflected row offsets (np 'reflect': -1 -> 1, H -> H-2)
    int hoff[K];
#pragma unroll
    for (int i = 0; i < K; ++i) {
        int hv = h + i - PADR;
        hv = (hv < 0) ? -hv : hv;
        hv = (hv >= H) ? (2 * H - 2 - hv) : hv;
        hoff[i] = hv << 9;
    }
    // reflected halo columns (only w0==0 / w0==504 actually reflect)
    int wl0 = w0 - 2; wl0 = (wl0 < 0) ? -wl0 : wl0;
    int wl1 = w0 - 1; wl1 = (wl1 < 0) ? -wl1 : wl1;
    int wr0 = w0 + 8; wr0 = (wr0 >= W) ? (2 * W - 2 - wr0) : wr0;
    int wr1 = w0 + 9; wr1 = (wr1 >= W) ? (2 * W - 2 - wr1) : wr1;

    float win[K][12];
#pragma unroll
    for (int i = 0; i < K; ++i) {
        const float* rp = xp + hoff[i];
        float4 m0 = *(const float4*)(rp + w0);
        float4 m1 = *(const float4*)(rp + w0 + 4);
        win[i][2] = m0.x; win[i][3] = m0.y; win[i][4] = m0.z; win[i][5] = m0.w;
        win[i][6] = m1.x; win[i][7] = m1.y; win[i][8] = m1.z; win[i][9] = m1.w;
        win[i][0]  = rp[wl0];
        win[i][1]  = rp[wl1];
        win[i][10] = rp[wr0];
        win[i][11] = rp[wr1];
    }

    v2f cc[4], ws[4], acc[4];
#pragma unroll
    for (int q = 0; q < 4; ++q) {
        cc[q][0] = win[2][2 * q + 2];
        cc[q][1] = win[2][2 * q + 3];
        ws[q] = (v2f){0.f, 0.f};
        acc[q] = (v2f){0.f, 0.f};
    }

#pragma unroll
    for (int i = 0; i < K; ++i) {
#pragma unroll
        for (int j = 0; j < K; ++j) {
            float lwv = lsk[i * K + j];
            v2f lsp = { lwv, lwv };
#pragma unroll
            for (int q = 0; q < 4; ++q) {
                v2f v = { win[i][2 * q + j], win[i][2 * q + j + 1] };
                v2f d = v - cc[q];
                v2f arg = __builtin_elementwise_fma(d * c2v, d, lsp);
                v2f wq;
                wq[0] = __builtin_amdgcn_exp2f(arg[0]);
                wq[1] = __builtin_amdgcn_exp2f(arg[1]);
                ws[q] += wq;
                acc[q] = __builtin_elementwise_fma(wq, v, acc[q]);
            }
        }
    }

    float4 o0, o1;
    o0.x = acc[0][0] * __builtin_amdgcn_rcpf(ws[0][0] + 1e-8f);
    o0.y = acc[0][1] * __builtin_amdgcn_rcpf(ws[0][1] + 1e-8f);
    o0.z = acc[1][0] * __builtin_amdgcn_rcpf(ws[1][0] + 1e-8f);
    o0.w = acc[1][1] * __builtin_amdgcn_rcpf(ws[1][1] + 1e-8f);
    o1.x = acc[2][0] * __builtin_amdgcn_rcpf(ws[2][0] + 1e-8f);
    o1.y = acc[2][1] * __builtin_amdgcn_rcpf(ws[2][1] + 1e-8f);
    o1.z = acc[3][0] * __builtin_amdgcn_rcpf(ws[3][0] + 1e-8f);
    o1.w = acc[3][1] * __builtin_amdgcn_rcpf(ws[3][1] + 1e-8f);
    *(float4*)(out + p0)     = o0;
    *(float4*)(out + p0 + 4) = o1;
}

extern "C" void kernel_launch(void* const* d_in, const int* in_sizes, int n_in,
                              void* d_out, int out_size, void* d_ws, size_t ws_size,
                              hipStream_t stream) {
    const float* x  = (const float*)d_in[0];
    const float* sk = (const float*)d_in[1];
    const float* sc = (const float*)d_in[2];
    float* out = (float*)d_out;

    const int total = in_sizes[0];             // 3,145,728
    const int blocks = total / (256 * 8);      // 1536, exact cover
    bilateral_kernel<<<blocks, 256, 0, stream>>>(x, sk, sc, out);
}